// Round 19
// baseline (26.619 us; speedup 1.0000x reference)
//
#include <hip/hip_runtime.h>

// CWT, truncated direct correlation, REAL PART ONLY (harness validates
// out_size = B*128*N float32 = real part of the complex64 reference).
// u-shifted: y[n] = sum_{u=1..T} xpad[n+u]*tw[u], xpad[i]=x[i-8192] (0 out),
// tw[u]=exp(-(u-1)^2/2sig^2)*cos(2pi*(u-1)/scale), sig=6*scale/2pi,
// T=ceil(4*sigma)+1 <= 246 (ALPHA=4: validated absmax 0.125 vs thr 0.445).
// ch%4 -> x row, ch%32 -> wavelet; 4|32 -> 32 unique channels, 4 copies.
// y == 0 exactly for n < 7946; zero boundary used: n < 7936.
//
// R18 lesson: R14(24.0) == R15(24.3) despite -40% cycles & perfect balance.
// Model fitting ALL rounds: execution at idle-ish SCLK (~0.6 GHz), duration =
// per-SIMD serial cycles / low clock. Lever: cut per-SIMD cycles via MORE,
// SHORTER waves. R19: unit = tile x scale-pair; 2112 one-wave blocks
// (2.06/SIMD), NO per-wave tap build (taps in ws via prep, L2-hot), NO LDS
// (xpad in ws, R10-validated window indexing), per-wave ~3.2K cyc.

#define NPIX   16384
#define PI_F   3.14159265358979f
#define ALSIG  3.81972f               // 4 * 6/(2*pi)
#define TSZ    256                    // tap floats per scale (u-idx, 0-padded)
#define TAPS_F (32 * TSZ)             // 8192 floats
#define XROW   16768                  // [8192 zeros][x row 16384][192 pad]
#define TMAX   246
#define NWT    33                     // working tiles 31..63
#define NUNIT  (NWT * 64)             // 2112 blocks
#define ZF4    1984                   // zero float4s per (b,ch) row
#define ZTOT   (512 * ZF4)            // 1015808 zero float4s
#define ZPW    481                    // per-wave zero quota (2112*481 covers)

__global__ __launch_bounds__(256) void prep_kernel(
    const float* __restrict__ x,
    const float* __restrict__ scales,
    float* __restrict__ ws)
{
    const int idx = blockIdx.x * 256 + threadIdx.x;
    if (blockIdx.x < 262) {                 // xpad: 16*16768/4 = 67072 float4
        float4* xp4 = reinterpret_cast<float4*>(ws + TAPS_F);
        const int row = idx / (XROW / 4);
        const int i   = (idx % (XROW / 4)) * 4;
        float4 v = {0.f, 0.f, 0.f, 0.f};
        if (i >= 8192)                       // i-8192 <= 8572 < NPIX always
            v = *reinterpret_cast<const float4*>(x + (size_t)row * NPIX + (i - 8192));
        xp4[idx] = v;
    } else {                                 // taps: 32*256 floats, u-indexed
        const int t = idx - 262 * 256;       // 0..8191
        const int s = t >> 8, u = t & 255;
        const float scale = scales[s];
        const float sig   = 0.954930f * scale;          // 6*sc/(2*pi)
        int T = (int)ceilf(ALSIG * scale) + 1;
        if (T > TMAX) T = TMAX;
        float v = 0.f;
        if (u >= 1 && u <= T) {
            const float tf = (float)(u - 1);
            v = __expf(-0.5f * tf * tf / (sig * sig))
              * __cosf(2.f * PI_F * tf / scale);
        }
        ws[t] = v;
    }
}

// 16 taps vs 20-float shared window, 4 outputs
#define BURST(Q0, Q1, Q2, Q3, A0, A1, A2, A3)                                \
    do {                                                                     \
        const float tk[16] = {Q0.x,Q0.y,Q0.z,Q0.w, Q1.x,Q1.y,Q1.z,Q1.w,      \
                              Q2.x,Q2.y,Q2.z,Q2.w, Q3.x,Q3.y,Q3.z,Q3.w};     \
        _Pragma("unroll")                                                    \
        for (int k = 0; k < 16; ++k) {                                       \
            A0 = fmaf(tk[k], e[k + 0], A0);                                  \
            A1 = fmaf(tk[k], e[k + 1], A1);                                  \
            A2 = fmaf(tk[k], e[k + 2], A2);                                  \
            A3 = fmaf(tk[k], e[k + 3], A3);                                  \
        }                                                                    \
    } while (0)

__global__ __launch_bounds__(64) void cwt_kernel(
    const float* __restrict__ scales,
    const float* __restrict__ ws,
    float* __restrict__ out)
{
    const int lane = threadIdx.x;
    const int Bk   = blockIdx.x;            // 0..2111
    const int tw   = Bk % NWT;              // tile 31+tw; mod 33: no aliasing
    const int rest = Bk / NWT;              // 0..63
    const int b    = rest >> 4;
    const int p    = rest & 15;
    const int c    = p >> 2;                // channel class (x row)
    const int j    = p & 3;
    const int sLO  = c + 4 * j;             // pair: shares x row, sum ~const
    const int sHI  = c + 28 - 4 * j;

    float4* out4 = reinterpret_cast<float4*>(out);

    // ---- zero duty: flat f4 range [481*Bk, +481) of the zero region ----
    {
        const float4 z4 = {0.f, 0.f, 0.f, 0.f};
        const int zbase = Bk * ZPW;
        #pragma unroll
        for (int r = 0; r < 8; ++r) {
            if (r < 7 || lane < 33) {       // 481 = 7*64 + 33
                const int z = zbase + (r << 6) + lane;
                if (z < ZTOT) {
                    const int row = z / ZF4;            // (b,ch) 0..511
                    const int col = z - row * ZF4;
                    out4[((size_t)row << 12) + col] = z4;
                }
            }
        }
    }

    // ---- per-pair params ----
    const float scLO = scales[sLO], scHI = scales[sHI];
    int TLO = (int)ceilf(ALSIG * scLO) + 1; if (TLO > TMAX) TLO = TMAX;
    int THI = (int)ceilf(ALSIG * scHI) + 1; if (THI > TMAX) THI = TMAX;
    const int nGlo = (TLO + 16) >> 4;
    const int nGhi = (THI + 16) >> 4;       // <= 16; sHI > sLO -> nGhi >= nGlo

    const int n0 = (31 + tw) << 8;          // 7936..16128
    const float4* xq  = reinterpret_cast<const float4*>(
                            ws + TAPS_F + (size_t)(b * 4 + c) * XROW)
                        + (n0 >> 2) + lane;
    const float4* tLO = reinterpret_cast<const float4*>(ws + sLO * TSZ);
    const float4* tHI = reinterpret_cast<const float4*>(ws + sHI * TSZ);

    float l0=0.f,l1=0.f,l2=0.f,l3=0.f, h0=0.f,h1=0.f,h2=0.f,h3=0.f;

    float4 w0 = xq[0], w1 = xq[1], w2 = xq[2], w3 = xq[3], w4 = xq[4];
    for (int g = 0; g < nGhi; ++g) {
        const int jq = g << 2;
        const float e[20] = {w0.x,w0.y,w0.z,w0.w, w1.x,w1.y,w1.z,w1.w,
                             w2.x,w2.y,w2.z,w2.w, w3.x,w3.y,w3.z,w3.w,
                             w4.x,w4.y,w4.z,w4.w};
        if (g < nGlo) {
            const float4 q0 = tLO[jq+0], q1 = tLO[jq+1],
                         q2 = tLO[jq+2], q3 = tLO[jq+3];
            BURST(q0, q1, q2, q3, l0, l1, l2, l3);
        }
        {
            const float4 q0 = tHI[jq+0], q1 = tHI[jq+1],
                         q2 = tHI[jq+2], q3 = tHI[jq+3];
            BURST(q0, q1, q2, q3, h0, h1, h2, h3);
        }
        // rolling window: advance 16 floats (reads overrun into xpad pad: ok)
        w0 = w4; w1 = xq[jq+5]; w2 = xq[jq+6]; w3 = xq[jq+7]; w4 = xq[jq+8];
    }

    // ---- store: 2 scales x 4 channel copies ----
    const int of4 = (n0 >> 2) + lane;
    const float4 vL = {l0, l1, l2, l3};
    const float4 vH = {h0, h1, h2, h3};
    #pragma unroll
    for (int q = 0; q < 4; ++q) {
        out4[((size_t)(b*128 + sLO + 32*q) << 12) + of4] = vL;
        out4[((size_t)(b*128 + sHI + 32*q) << 12) + of4] = vH;
    }
}

extern "C" void kernel_launch(void* const* d_in, const int* in_sizes, int n_in,
                              void* d_out, int out_size, void* d_ws, size_t ws_size,
                              hipStream_t stream) {
    const float* x      = (const float*)d_in[0];
    const float* scales = (const float*)d_in[1];
    float* out          = (float*)d_out;
    float* ws           = (float*)d_ws;   // taps 32KB + xpad 1.05MB

    prep_kernel<<<dim3(294), 256, 0, stream>>>(x, scales, ws);
    cwt_kernel<<<dim3(NUNIT), 64, 0, stream>>>(scales, ws, out);
}

// Round 20
// 25.404 us; speedup vs baseline: 1.0479x; 1.0479x over previous
//
#include <hip/hip_runtime.h>

// CWT, truncated direct correlation, REAL PART ONLY.
// y[n] = sum_{u=1..T} xpad[n+u]*tw[u]; xpad[i]=x[i-8192] (0 outside);
// tw[u]=exp(-(u-1)^2/2sig^2)*cos(2pi*(u-1)/scale); sig=6*scale/2pi;
// T=ceil(4*sigma)+1 <= 246 (validated absmax 0.125 vs threshold 0.445).
// ch%4 -> x row, ch%32 -> wavelet; 32 unique channels, 4 copies.
//
// R19 lesson: wave shape null; all rounds fit "per-SIMD issue cycles / low
// idle clock". R20: halve issue cycles with v_dot2_f32_f16 (2 fp16 MAC +
// fp32 acc per instr). Alignment solved by TWO pre-shifted half images
// (xh1[i]=xpad[i+1], xh0s[i]=xpad[i+2]): outputs r0/r1 use words k=0..7,
// r2/r3 words k=1..8 of one rolling 10-word window; all half2 word-aligned.

typedef _Float16 half2v __attribute__((ext_vector_type(2)));
typedef unsigned int u32;

#define NPIX   16384
#define PI_F   3.14159265358979f
#define ALSIG  3.81972f               // 4 * 6/(2*pi)
#define TMAX   246
#define NWT    33                     // working tiles 31..63
#define NUNIT  (NWT * 64)             // 2112 blocks
#define ZF4    1984
#define ZTOT   (512 * ZF4)
#define ZPW    481
#define WPR    8384                   // half2 words per padded row (16768/2)
#define TAPW_OFF 0                    // taps: 32*128 words (16 KB)
#define XH0_OFF  4096                 // xh0s: 16*WPR words
#define XH1_OFF  (4096 + 16 * WPR)   // xh1:  16*WPR words

#if __has_builtin(__builtin_amdgcn_fdot2)
#define FDOT2(a, b, c) __builtin_amdgcn_fdot2((a), (b), (c), false)
#else
#define FDOT2(a, b, c) fmaf((float)(a).x, (float)(b).x, \
                        fmaf((float)(a).y, (float)(b).y, (c)))
#endif
#define H2(W) __builtin_bit_cast(half2v, (W))

__global__ __launch_bounds__(256) void prep_kernel(
    const float* __restrict__ x,
    const float* __restrict__ scales,
    u32* __restrict__ ws)
{
    const int idx = blockIdx.x * 256 + threadIdx.x;
    if (blockIdx.x < 16) {                     // taps: 32 scales x 128 words
        const int s = idx >> 7, k = idx & 127;
        const float scale = scales[s];
        const float sig   = 0.954930f * scale;
        int T = (int)ceilf(ALSIG * scale) + 1; if (T > TMAX) T = TMAX;
        float t1 = 0.f, t2 = 0.f;
        const int u1 = 2 * k + 1, u2 = 2 * k + 2;
        if (u1 <= T) { const float tf = (float)(u1 - 1);
            t1 = __expf(-0.5f * tf * tf / (sig * sig)) * __cosf(2.f * PI_F * tf / scale); }
        if (u2 <= T) { const float tf = (float)(u2 - 1);
            t2 = __expf(-0.5f * tf * tf / (sig * sig)) * __cosf(2.f * PI_F * tf / scale); }
        half2v h = { (_Float16)t1, (_Float16)t2 };
        ws[TAPW_OFF + idx] = __builtin_bit_cast(u32, h);
    } else {                                   // xh0s then xh1: 2*16*WPR words
        const int w   = idx - 16 * 256;        // 0 .. 268287 (exact)
        const int arr = w / (16 * WPR);        // 0: xh0s(shift2) 1: xh1(shift1)
        const int w2  = w - arr * (16 * WPR);
        const int row = w2 / WPR, j = w2 - row * WPR;
        const int shift = arr ? 1 : 2;
        const int i0 = 2 * j + shift;          // xpad index of first half
        const float* xr = x + (size_t)row * NPIX;
        const float a = (i0     >= 8192) ? xr[i0 - 8192] : 0.f;  // <=8577: safe
        const float b = (i0 + 1 >= 8192) ? xr[i0 - 8191] : 0.f;
        half2v h = { (_Float16)a, (_Float16)b };
        ws[(arr ? XH1_OFF : XH0_OFF) + w2] = __builtin_bit_cast(u32, h);
    }
}

#define LD2(P, O) (*reinterpret_cast<const uint2*>((P) + (O)))

__global__ __launch_bounds__(64) void cwt_kernel(
    const float* __restrict__ scales,
    const u32* __restrict__ ws,
    float* __restrict__ out)
{
    const int lane = threadIdx.x;
    const int Bk   = blockIdx.x;            // 0..2111
    const int tw   = Bk % NWT;              // tile 31+tw (mod 33: no aliasing)
    const int rest = Bk / NWT;
    const int b    = rest >> 4;
    const int p    = rest & 15;
    const int c    = p >> 2;
    const int j    = p & 3;
    const int sLO  = c + 4 * j;             // balanced pair, same x row
    const int sHI  = c + 28 - 4 * j;

    float4* out4 = reinterpret_cast<float4*>(out);

    // ---- zero duty: flat f4 range [481*Bk, +481) ----
    {
        const float4 z4 = {0.f, 0.f, 0.f, 0.f};
        const int zbase = Bk * ZPW;
        #pragma unroll
        for (int r = 0; r < 8; ++r) {
            if (r < 7 || lane < 33) {
                const int z = zbase + (r << 6) + lane;
                if (z < ZTOT) {
                    const int row = z / ZF4;
                    const int col = z - row * ZF4;
                    out4[((size_t)row << 12) + col] = z4;
                }
            }
        }
    }

    const float scLO = scales[sLO], scHI = scales[sHI];
    int TLO = (int)ceilf(ALSIG * scLO) + 1; if (TLO > TMAX) TLO = TMAX;
    int THI = (int)ceilf(ALSIG * scHI) + 1; if (THI > TMAX) THI = TMAX;
    const int nGlo = (TLO + 15) >> 4;
    const int nGhi = (THI + 15) >> 4;       // <= 16

    const int n0 = (31 + tw) << 8;
    const int m  = n0 + 4 * lane;           // even
    const int rowoff = (b * 4 + c) * WPR + (m >> 1);   // word base (even)
    const u32* X1 = ws + XH1_OFF + rowoff;  // r0: words k, r2: words k+1
    const u32* X0 = ws + XH0_OFF + rowoff;  // r1: words k, r3: words k+1
    const u32* TL = ws + TAPW_OFF + sLO * 128;
    const u32* TH = ws + TAPW_OFF + sHI * 128;

    float l0=0.f,l1=0.f,l2=0.f,l3=0.f, h0=0.f,h1=0.f,h2=0.f,h3=0.f;

    // rolling 10-word windows per parity (uint2 loads, all even offsets)
    uint2 A0 = LD2(X1,0), A1 = LD2(X1,2), A2 = LD2(X1,4),
          A3 = LD2(X1,6), A4 = LD2(X1,8);
    uint2 B0 = LD2(X0,0), B1 = LD2(X0,2), B2 = LD2(X0,4),
          B3 = LD2(X0,6), B4 = LD2(X0,8);

    for (int g = 0; g < nGhi; ++g) {
        const int tb = g << 3;
        const uint4 tl0 = *reinterpret_cast<const uint4*>(TL + tb);
        const uint4 tl1 = *reinterpret_cast<const uint4*>(TL + tb + 4);
        const uint4 th0 = *reinterpret_cast<const uint4*>(TH + tb);
        const uint4 th1 = *reinterpret_cast<const uint4*>(TH + tb + 4);

        const u32 w1[10] = {A0.x,A0.y,A1.x,A1.y,A2.x,A2.y,A3.x,A3.y,A4.x,A4.y};
        const u32 w0[10] = {B0.x,B0.y,B1.x,B1.y,B2.x,B2.y,B3.x,B3.y,B4.x,B4.y};
        const u32 tlw[8] = {tl0.x,tl0.y,tl0.z,tl0.w, tl1.x,tl1.y,tl1.z,tl1.w};
        const u32 thw[8] = {th0.x,th0.y,th0.z,th0.w, th1.x,th1.y,th1.z,th1.w};

        // prefetch next window (values above already copied to w1/w0)
        if (g + 1 < nGhi) {
            const int nb = ((g + 1) << 3);
            A0 = A4; A1 = LD2(X1, nb + 2); A2 = LD2(X1, nb + 4);
            A3 = LD2(X1, nb + 6); A4 = LD2(X1, nb + 8);
            B0 = B4; B1 = LD2(X0, nb + 2); B2 = LD2(X0, nb + 4);
            B3 = LD2(X0, nb + 6); B4 = LD2(X0, nb + 8);
        }

        const bool dlo = (g < nGlo);
        #pragma unroll
        for (int k = 0; k < 8; ++k) {
            const half2v xa = H2(w1[k]);       // r=0
            const half2v xb = H2(w0[k]);       // r=1
            const half2v xc = H2(w1[k + 1]);   // r=2
            const half2v xd = H2(w0[k + 1]);   // r=3
            const half2v tl = H2(tlw[k]);
            const half2v th = H2(thw[k]);
            if (dlo) {
                l0 = FDOT2(xa, tl, l0); l1 = FDOT2(xb, tl, l1);
                l2 = FDOT2(xc, tl, l2); l3 = FDOT2(xd, tl, l3);
            }
            h0 = FDOT2(xa, th, h0); h1 = FDOT2(xb, th, h1);
            h2 = FDOT2(xc, th, h2); h3 = FDOT2(xd, th, h3);
        }
    }

    // ---- store: 2 scales x 4 channel copies ----
    const int of4 = (n0 >> 2) + lane;
    const float4 vL = {l0, l1, l2, l3};
    const float4 vH = {h0, h1, h2, h3};
    #pragma unroll
    for (int q = 0; q < 4; ++q) {
        out4[((size_t)(b * 128 + sLO + 32 * q) << 12) + of4] = vL;
        out4[((size_t)(b * 128 + sHI + 32 * q) << 12) + of4] = vH;
    }
}

extern "C" void kernel_launch(void* const* d_in, const int* in_sizes, int n_in,
                              void* d_out, int out_size, void* d_ws, size_t ws_size,
                              hipStream_t stream) {
    const float* x      = (const float*)d_in[0];
    const float* scales = (const float*)d_in[1];
    float* out          = (float*)d_out;
    u32* ws             = (u32*)d_ws;     // taps 16KB + 2 half images ~1.05MB

    prep_kernel<<<dim3(1064), 256, 0, stream>>>(x, scales, ws);
    cwt_kernel<<<dim3(NUNIT), 64, 0, stream>>>(scales, ws, out);
}

// Round 21
// 23.869 us; speedup vs baseline: 1.1152x; 1.0643x over previous
//
#include <hip/hip_runtime.h>

// CWT, truncated direct correlation, REAL PART ONLY (harness validates
// out_size = B*128*N float32 = real part of the complex64 reference).
//   y[n] = sum_{u=1..T} xpad[n+u]*tw[u], xpad[i]=x[i-8192] (0 outside),
//   tw[u] = exp(-(u-1)^2/2sig^2)*cos(2pi*(u-1)/scale), sig = 6*scale/2pi,
//   T = ceil(5*sigma)+1 <= 307  (validated absmax 0.0625 vs threshold 0.445).
// ch%4 -> x row, ch%32 -> wavelet; 4|32 -> 32 unique channels, 4 copies.
//
// FINAL (R21 = R14 restored, best measured: 23.97 us).
// Evidence from 11 structural variants (R7-R20): FMA work /2.8, waves x4,
// LDS/global/VALU/fp16-dot2 operand paths, 1-3 dispatch splits, perfect
// 1-wave/SIMD balance -- ALL land 24-33 us. The ~24 us floor is a
// dispatch-environment constant (clock ramp + per-dispatch overhead under
// graph replay), not a memory/VALU roofline: co-captured fills sustain
// 6.5 TB/s. This kernel: single dispatch, 1088 one-wave blocks, taps+window
// in LDS (built in-kernel), 4-scale window reuse, rotation block map.

#define NPIX   16384
#define NSCALE 32
#define ALPHA  5.0f
#define PI_F   3.14159265358979f
#define TPS4   80        // tap float4s per scale (320 floats, zero-padded)
#define SPAN4  152       // staged window float4s (608 floats)
#define WT0    30
#define NWT    34
#define NZT    30
#define NBLOCK (NWT * 32)   // 1088

#define FMA_SCALE(T0, T1, T2, T3, A0, A1, A2, A3)                            \
    do {                                                                     \
        const float tk[16] = {T0.x,T0.y,T0.z,T0.w, T1.x,T1.y,T1.z,T1.w,      \
                              T2.x,T2.y,T2.z,T2.w, T3.x,T3.y,T3.z,T3.w};     \
        _Pragma("unroll")                                                    \
        for (int t = 0; t < 16; ++t) {                                       \
            A0 = fmaf(tk[t], e[t + 0], A0);                                  \
            A1 = fmaf(tk[t], e[t + 1], A1);                                  \
            A2 = fmaf(tk[t], e[t + 2], A2);                                  \
            A3 = fmaf(tk[t], e[t + 3], A3);                                  \
        }                                                                    \
    } while (0)

__global__ __launch_bounds__(64) void cwt_kernel(
    const float* __restrict__ x,
    const float* __restrict__ scales,
    float* __restrict__ out)
{
    __shared__ float4 tl4[4][TPS4];   // 4 scales x 320 taps  = 5 KB
    __shared__ float4 xs4[SPAN4];     // 608-float x window   = 2.4 KB

    const int lane = threadIdx.x;
    const int Bk   = blockIdx.x;
    const int q    = Bk / NWT;               // 0..31 = (b,c,sub)
    const int r34  = Bk - q * NWT;           // 0..33
    const int b    = q >> 3;
    const int c    = (q >> 1) & 3;
    const int sub  = q & 1;
    int twr = r34 + q; if (twr >= NWT) twr -= NWT;   // rotation, bijective per q
    const int n0   = (WT0 + twr) << 8;
    const int sb   = c + (sub << 2);         // scales sb + 8k, k=0..3 (ascending)

    const size_t cstride = (size_t)NSCALE * NPIX;

    // ---- zero duty: block's r34 (<30) names the zero tile it fills ----
    if (r34 < NZT) {
        const float4 z = {0.f, 0.f, 0.f, 0.f};
        #pragma unroll
        for (int k = 0; k < 4; ++k) {
            float* zp = out + ((size_t)b * 128 + (sb + 8 * k)) * NPIX
                            + (r34 << 8) + (lane << 2);
            #pragma unroll
            for (int q4 = 0; q4 < 4; ++q4)
                *reinterpret_cast<float4*>(zp + (size_t)q4 * cstride) = z;
        }
    }

    // ---- per-scale params (static names, rule #20) ----
    const float sc0 = scales[sb],      sc1 = scales[sb + 8];
    const float sc2 = scales[sb + 16], sc3 = scales[sb + 24];
#define PARAMS(SC, SG, TT, W2, C2)                                            \
    const float SG = 6.0f * SC / (2.0f * PI_F);                               \
    int TT = (int)ceilf(ALPHA * SG) + 1; if (TT > 307) TT = 307;              \
    const float W2 = 2.0f * PI_F / SC;                                        \
    const float C2 = -0.5f / (SG * SG);
    PARAMS(sc0, sg0, T0, w2_0, c2_0)
    PARAMS(sc1, sg1, T1, w2_1, c2_1)
    PARAMS(sc2, sg2, T2, w2_2, c2_2)
    PARAMS(sc3, sg3, T3, w2_3, c2_3)
#undef PARAMS

    // ---- taps into LDS: u-indexed, tl[k][u] = tw_k[u], zero-padded ----
    {
        float* tl0 = reinterpret_cast<float*>(tl4[0]);
        float* tl1 = reinterpret_cast<float*>(tl4[1]);
        float* tl2 = reinterpret_cast<float*>(tl4[2]);
        float* tl3 = reinterpret_cast<float*>(tl4[3]);
        #pragma unroll
        for (int m = 0; m < 5; ++m) {
            const int u = lane + (m << 6);          // 0..319
            const float tf = (float)(u - 1);
            const float t2 = tf * tf;
#define TAP(DST, TT, C2, W2)                                                  \
            DST[u] = (u >= 1 && u <= TT)                                      \
                   ? __expf(C2 * t2) * __cosf(W2 * tf) : 0.0f;
            TAP(tl0, T0, c2_0, w2_0)
            TAP(tl1, T1, c2_1, w2_1)
            TAP(tl2, T2, c2_2, w2_2)
            TAP(tl3, T3, c2_3, w2_3)
#undef TAP
        }
    }

    // ---- stage x window: xs[i] = xpad[n0 + i] = x[n0 + i - 8192] ----
    {
        const float* xrow = x + (size_t)(b * 4 + c) * NPIX;
        #pragma unroll
        for (int m = 0; m < 3; ++m) {
            const int i4 = lane + (m << 6);
            if (i4 < SPAN4) {
                const int gi = n0 - 8192 + (i4 << 2);
                float4 v = {0.f, 0.f, 0.f, 0.f};
                if (gi >= 0)
                    v = *reinterpret_cast<const float4*>(xrow + gi);
                xs4[i4] = v;
            }
        }
    }
    // single wave: in-wave LDS write->read ordering via compiler lgkmcnt.

    const int nG0 = (T0 >> 4) + 1, nG1 = (T1 >> 4) + 1;
    const int nG2 = (T2 >> 4) + 1, nGmax = (T3 >> 4) + 1;   // ascending T
    const int umin = 8192 - n0 - 255;
    const int g0   = (umin > 0) ? (umin >> 4) : 0;

    float a00=0.f,a01=0.f,a02=0.f,a03=0.f, a10=0.f,a11=0.f,a12=0.f,a13=0.f;
    float a20=0.f,a21=0.f,a22=0.f,a23=0.f, a30=0.f,a31=0.f,a32=0.f,a33=0.f;

    if (g0 < nGmax) {
        const int jw = lane + (g0 << 2);
        float4 w0 = xs4[jw],   w1 = xs4[jw+1], w2 = xs4[jw+2],
               w3 = xs4[jw+3], w4 = xs4[jw+4];

        for (int g = g0; g < nGmax; ++g) {
            const int jt = g << 2;
            const int jx = lane + jt;

            // scale-A taps first; later scales' loads interleave with FMAs
            const float4 tA0 = tl4[0][jt], tA1 = tl4[0][jt+1],
                         tA2 = tl4[0][jt+2], tA3 = tl4[0][jt+3];
            const float e[20] = {w0.x,w0.y,w0.z,w0.w, w1.x,w1.y,w1.z,w1.w,
                                 w2.x,w2.y,w2.z,w2.w, w3.x,w3.y,w3.z,w3.w,
                                 w4.x,w4.y,w4.z,w4.w};
            const float4 tB0 = tl4[1][jt], tB1 = tl4[1][jt+1],
                         tB2 = tl4[1][jt+2], tB3 = tl4[1][jt+3];
            if (g < nG0) FMA_SCALE(tA0, tA1, tA2, tA3, a00, a01, a02, a03);
            const float4 tC0 = tl4[2][jt], tC1 = tl4[2][jt+1],
                         tC2 = tl4[2][jt+2], tC3 = tl4[2][jt+3];
            if (g < nG1) FMA_SCALE(tB0, tB1, tB2, tB3, a10, a11, a12, a13);
            const float4 tD0 = tl4[3][jt], tD1 = tl4[3][jt+1],
                         tD2 = tl4[3][jt+2], tD3 = tl4[3][jt+3];
            if (g < nG2) FMA_SCALE(tC0, tC1, tC2, tC3, a20, a21, a22, a23);
            // next-group window loads issued before the last FMA burst
            const float4 x1 = xs4[jx+5], x2 = xs4[jx+6],
                         x3 = xs4[jx+7], x4 = xs4[jx+8];
            FMA_SCALE(tD0, tD1, tD2, tD3, a30, a31, a32, a33);

            w0 = w4; w1 = x1; w2 = x2; w3 = x3; w4 = x4;
        }
    }

    // ---- store: 4 scales x 4 channel copies ----
    float* ob = out + (size_t)b * 128 * NPIX + n0 + (lane << 2);
    #pragma unroll
    for (int k = 0; k < 4; ++k) {
        float4 v;
        if (k == 0) v = make_float4(a00, a01, a02, a03);
        if (k == 1) v = make_float4(a10, a11, a12, a13);
        if (k == 2) v = make_float4(a20, a21, a22, a23);
        if (k == 3) v = make_float4(a30, a31, a32, a33);
        float* os = ob + (size_t)(sb + 8 * k) * NPIX;
        #pragma unroll
        for (int q4 = 0; q4 < 4; ++q4)
            *reinterpret_cast<float4*>(os + (size_t)q4 * cstride) = v;
    }
}

extern "C" void kernel_launch(void* const* d_in, const int* in_sizes, int n_in,
                              void* d_out, int out_size, void* d_ws, size_t ws_size,
                              hipStream_t stream) {
    const float* x      = (const float*)d_in[0];
    const float* scales = (const float*)d_in[1];
    float* out          = (float*)d_out;

    cwt_kernel<<<dim3(NBLOCK), 64, 0, stream>>>(x, scales, out);
}